// Round 8
// baseline (325.405 us; speedup 1.0000x reference)
//
#include <hip/hip_runtime.h>
#include <hip/hip_bf16.h>

#define M_NODES 100000
#define N_EDGES 1600000
#define SCAN_NB 98    // ceil(100000 / 1024)
#define GB 1563       // gemm blocks: ceil(100000/64)
#define CNT_B 1024    // count blocks (8 edges/thread)
#define FILL_B 1024   // fill blocks (8 edges/thread)

typedef __attribute__((ext_vector_type(8))) short short8;
typedef __attribute__((ext_vector_type(4))) float f32x4;
typedef __attribute__((address_space(3))) void lds_t;
typedef const __attribute__((address_space(1))) void gld_t;

__device__ __forceinline__ ushort f2bf(float f) {
    union { float f; uint u; } x; x.f = f;
    uint r = x.u + 0x7fffu + ((x.u >> 16) & 1u);   // RNE
    return (ushort)(r >> 16);
}
__device__ __forceinline__ float bflo(uint v) {
    union { uint u; float f; } x; x.u = v << 16; return x.f;
}
__device__ __forceinline__ float bfhi(uint v) {
    union { uint u; float f; } x; x.u = v & 0xffff0000u; return x.f;
}

// ---------------------------------------------------------------------------
// fused weight prep (transpose+bf16)  ||  degree count + rank (LDS-free!)
// blocks 0..127: Wt_in; 128..191: Wt_c0; 192..255: Wt_c1; 256..: count
// cnt must be zeroed beforehand (hipMemsetAsync).
// ---------------------------------------------------------------------------
__global__ void __launch_bounds__(256)
k_prep_count(const float* __restrict__ W_in, const float* __restrict__ W_c0,
             const float* __restrict__ W_c1, ushort* __restrict__ Wt_in,
             ushort* __restrict__ Wt_c0, ushort* __restrict__ Wt_c1,
             const int* __restrict__ dst, int* __restrict__ cnt,
             ushort* __restrict__ rank) {
    const int b = blockIdx.x, t = threadIdx.x;
    if (b < 128) {
        int i = b * 256 + t;              // c = i>>8, k = i&255
        Wt_in[i] = f2bf(W_in[(size_t)(i & 255) * 128 + (i >> 8)]);
    } else if (b < 192) {
        int i = (b - 128) * 256 + t;      // c = i>>7, k = i&127
        Wt_c0[i] = f2bf(W_c0[(size_t)(i & 127) * 128 + (i >> 7)]);
    } else if (b < 256) {
        int i = (b - 192) * 256 + t;
        Wt_c1[i] = f2bf(W_c1[(size_t)(i & 127) * 128 + (i >> 7)]);
    } else {
        // count: 8 edges/thread, all loads/atomics/stores independent (MLP=8)
        const int base = (b - 256) * 2048 + t;
        int d[8]; bool ok[8]; int r[8];
#pragma unroll
        for (int i = 0; i < 8; ++i) {
            int e = base + i * 256;
            ok[i] = e < N_EDGES;
            d[i] = ok[i] ? dst[e] : 0;
        }
#pragma unroll
        for (int i = 0; i < 8; ++i)
            if (ok[i]) r[i] = atomicAdd(&cnt[d[i]], 1);
#pragma unroll
        for (int i = 0; i < 8; ++i)
            if (ok[i]) rank[base + i * 256] = (ushort)r[i];
    }
}

// ---------------------------------------------------------------------------
// 3-phase exclusive scan (off) + dinv
// ---------------------------------------------------------------------------
__global__ void __launch_bounds__(256)
k_scanA(const int* __restrict__ cnt, int* __restrict__ bsum) {
    __shared__ int sh[256];
    const int b = blockIdx.x, t = threadIdx.x;
    int base = b * 1024 + t * 4;
    int s = 0;
#pragma unroll
    for (int j = 0; j < 4; ++j) {
        int i = base + j;
        if (i < M_NODES) s += cnt[i];
    }
    sh[t] = s;
    __syncthreads();
    for (int o = 128; o; o >>= 1) {
        if (t < o) sh[t] += sh[t + o];
        __syncthreads();
    }
    if (t == 0) bsum[b] = sh[0];
}

__global__ void __launch_bounds__(128)
k_scanB(int* __restrict__ bsum, int* __restrict__ off) {
    __shared__ int sh[128];
    const int t = threadIdx.x;
    int v = (t < SCAN_NB) ? bsum[t] : 0;
    sh[t] = v;
    __syncthreads();
    for (int o = 1; o < 128; o <<= 1) {
        int u = (t >= o) ? sh[t - o] : 0;
        __syncthreads();
        sh[t] += u;
        __syncthreads();
    }
    if (t < SCAN_NB) bsum[t] = sh[t] - v;  // exclusive
    if (t == 0) off[M_NODES] = N_EDGES;
}

__global__ void __launch_bounds__(256)
k_scanC(const int* __restrict__ cnt, const int* __restrict__ bsum,
        int* __restrict__ off, float* __restrict__ dinv) {
    __shared__ int sh[256];
    const int b = blockIdx.x, t = threadIdx.x;
    int base = b * 1024 + t * 4;
    int loc[4];
    int s = 0;
#pragma unroll
    for (int j = 0; j < 4; ++j) {
        int i = base + j;
        loc[j] = (i < M_NODES) ? cnt[i] : 0;
        s += loc[j];
    }
    sh[t] = s;
    __syncthreads();
    for (int o = 1; o < 256; o <<= 1) {
        int u = (t >= o) ? sh[t - o] : 0;
        __syncthreads();
        sh[t] += u;
        __syncthreads();
    }
    int run = bsum[b] + sh[t] - s;
#pragma unroll
    for (int j = 0; j < 4; ++j) {
        int i = base + j;
        if (i < M_NODES) {
            off[i] = run;
            dinv[i] = rsqrtf((float)(loc[j] + 1));
            run += loc[j];
        }
    }
}

// ---------------------------------------------------------------------------
// atomic-free CSR fill, LDS-free, 8 edges/thread (8 independent chains)
// csr[off[dst[e]] + rank[e]] = src[e]
// ---------------------------------------------------------------------------
__global__ void __launch_bounds__(256)
k_fill(const int* __restrict__ src, const int* __restrict__ dst,
       const int* __restrict__ off, const ushort* __restrict__ rank,
       int* __restrict__ csr) {
    const int base = blockIdx.x * 2048 + threadIdx.x;
    int d[8], s[8]; ushort r[8]; bool ok[8]; int o[8];
#pragma unroll
    for (int i = 0; i < 8; ++i) {
        int e = base + i * 256;
        ok[i] = e < N_EDGES;
        d[i] = ok[i] ? dst[e] : 0;
        s[i] = ok[i] ? src[e] : 0;
        r[i] = ok[i] ? rank[e] : 0;
    }
#pragma unroll
    for (int i = 0; i < 8; ++i) o[i] = ok[i] ? off[d[i]] : 0;
#pragma unroll
    for (int i = 0; i < 8; ++i)
        if (ok[i]) csr[o[i] + (int)r[i]] = s[i];
}

// ---------------------------------------------------------------------------
// MFMA GEMM: A[M,K] @ B[K,128], Bt[128][K] bf16.
// 64x128 tile, BK=64, 4 waves (2x2): wave = 32 rows x 64 cols, 2x4 frags.
// MODE 0: out = bf16(relu(A@B + bias));  MODE 1: out = bf16((A@B)*dinv[row])
// ---------------------------------------------------------------------------
template <int K, int MODE, bool AF32>
__global__ void __launch_bounds__(256)
k_gemm(const void* __restrict__ Av, const ushort* __restrict__ Bt,
       const float* __restrict__ bias, const float* __restrict__ dinv,
       ushort* __restrict__ out) {
    __shared__ ushort As[64 * 64];    // [row][k] 8 KB
    __shared__ ushort Bs[128 * 64];   // [col][k] 16 KB
    const int t = threadIdx.x;
    const int lane = t & 63, w = t >> 6;
    const int wr = w >> 1, wc = w & 1;
    const int l15 = lane & 15, l4 = lane >> 4;
    const int row0 = blockIdx.x * 64;

    f32x4 acc[2][4] = {};

    for (int k0 = 0; k0 < K; k0 += 64) {
#pragma unroll
        for (int i = 0; i < 4; ++i) {
            int idx = (i * 256 + t) * 8;          // bf16 elem index in tile
            int col = idx >> 6, kc = idx & 63;
            __builtin_amdgcn_global_load_lds(
                (gld_t*)(Bt + (size_t)col * K + k0 + kc),
                (lds_t*)(Bs + idx), 16, 0, 0);
        }
        if (AF32) {
            const float* A = (const float*)Av;
#pragma unroll
            for (int i = 0; i < 2; ++i) {
                int idx = (i * 256 + t) * 8;
                int r = idx >> 6, c = idx & 63;
                int gr = row0 + r; gr = gr < M_NODES ? gr : M_NODES - 1;
                const float4* gp = (const float4*)(A + (size_t)gr * K + k0 + c);
                float4 v0 = gp[0], v1 = gp[1];
                short8 p;
                p[0] = (short)f2bf(v0.x); p[1] = (short)f2bf(v0.y);
                p[2] = (short)f2bf(v0.z); p[3] = (short)f2bf(v0.w);
                p[4] = (short)f2bf(v1.x); p[5] = (short)f2bf(v1.y);
                p[6] = (short)f2bf(v1.z); p[7] = (short)f2bf(v1.w);
                *reinterpret_cast<short8*>(&As[idx]) = p;
            }
        } else {
            const ushort* A = (const ushort*)Av;
#pragma unroll
            for (int i = 0; i < 2; ++i) {
                int idx = (i * 256 + t) * 8;
                int r = idx >> 6, c = idx & 63;
                int gr = row0 + r; gr = gr < M_NODES ? gr : M_NODES - 1;
                __builtin_amdgcn_global_load_lds(
                    (gld_t*)(A + (size_t)gr * K + k0 + c),
                    (lds_t*)(As + idx), 16, 0, 0);
            }
        }
        __syncthreads();
#pragma unroll
        for (int kk = 0; kk < 2; ++kk) {
            short8 af[2], bw[4];
#pragma unroll
            for (int m = 0; m < 2; ++m)
                af[m] = *reinterpret_cast<const short8*>(
                    &As[(wr * 32 + m * 16 + l15) * 64 + kk * 32 + l4 * 8]);
#pragma unroll
            for (int n = 0; n < 4; ++n)
                bw[n] = *reinterpret_cast<const short8*>(
                    &Bs[(wc * 64 + n * 16 + l15) * 64 + kk * 32 + l4 * 8]);
#pragma unroll
            for (int m = 0; m < 2; ++m)
#pragma unroll
                for (int n = 0; n < 4; ++n)
                    acc[m][n] = __builtin_amdgcn_mfma_f32_16x16x32_bf16(
                        af[m], bw[n], acc[m][n], 0, 0, 0);
        }
        __syncthreads();
    }

    // epilogue: C[row][col], col = lane&15, row = (lane>>4)*4 + j
#pragma unroll
    for (int m = 0; m < 2; ++m) {
#pragma unroll
        for (int j = 0; j < 4; ++j) {
            int r = row0 + wr * 32 + m * 16 + l4 * 4 + j;
            if (r < M_NODES) {
                float sc = (MODE == 1) ? dinv[r] : 0.f;
#pragma unroll
                for (int n = 0; n < 4; ++n) {
                    int c = wc * 64 + n * 16 + l15;
                    float v = acc[m][n][j];
                    if (MODE == 0) v = fmaxf(v + bias[c], 0.f);
                    else v *= sc;
                    out[(size_t)r * 128 + c] = f2bf(v);
                }
            }
        }
    }
}

// ---------------------------------------------------------------------------
// neighbor accumulation core: 8-way unrolled, 8 independent acc pairs
// ---------------------------------------------------------------------------
__device__ __forceinline__ void
gather_accum(const uint* __restrict__ hs2, const int* __restrict__ csr,
             int beg, int end, int lane, float& ax, float& ay) {
    float px[8] = {}, py[8] = {};
    for (int b = beg; b < end; b += 64) {
        int m = end - b; if (m > 64) m = 64;
        int idx = (lane < m) ? csr[b + lane] : 0;
        int i = 0;
        for (; i + 8 <= m; i += 8) {
            uint v0 = hs2[(size_t)__shfl(idx, i + 0) * 64 + lane];
            uint v1 = hs2[(size_t)__shfl(idx, i + 1) * 64 + lane];
            uint v2 = hs2[(size_t)__shfl(idx, i + 2) * 64 + lane];
            uint v3 = hs2[(size_t)__shfl(idx, i + 3) * 64 + lane];
            uint v4 = hs2[(size_t)__shfl(idx, i + 4) * 64 + lane];
            uint v5 = hs2[(size_t)__shfl(idx, i + 5) * 64 + lane];
            uint v6 = hs2[(size_t)__shfl(idx, i + 6) * 64 + lane];
            uint v7 = hs2[(size_t)__shfl(idx, i + 7) * 64 + lane];
            px[0] += bflo(v0); py[0] += bfhi(v0);
            px[1] += bflo(v1); py[1] += bfhi(v1);
            px[2] += bflo(v2); py[2] += bfhi(v2);
            px[3] += bflo(v3); py[3] += bfhi(v3);
            px[4] += bflo(v4); py[4] += bfhi(v4);
            px[5] += bflo(v5); py[5] += bfhi(v5);
            px[6] += bflo(v6); py[6] += bfhi(v6);
            px[7] += bflo(v7); py[7] += bfhi(v7);
        }
        uint rv[7]; int rc = 0;
        for (; i < m; ++i) rv[rc++] = hs2[(size_t)__shfl(idx, i) * 64 + lane];
        for (int k = 0; k < rc; ++k) { px[k] += bflo(rv[k]); py[k] += bfhi(rv[k]); }
    }
    ax += ((px[0] + px[1]) + (px[2] + px[3])) + ((px[4] + px[5]) + (px[6] + px[7]));
    ay += ((py[0] + py[1]) + (py[2] + py[3])) + ((py[4] + py[5]) + (py[6] + py[7]));
}

// ---------------------------------------------------------------------------
// gather-aggregate (bf16): one wave per node, uint (2 bf16) per lane
// ---------------------------------------------------------------------------
__global__ void __launch_bounds__(256)
k_gather(const ushort* __restrict__ hs, const int* __restrict__ csr,
         const int* __restrict__ off, const float* __restrict__ dinv,
         const float* __restrict__ bias, ushort* __restrict__ out) {
    const int wid = threadIdx.x >> 6;
    const int lane = threadIdx.x & 63;
    const int n = blockIdx.x * 4 + wid;
    if (n >= M_NODES) return;

    const uint* hs2 = (const uint*)hs;
    uint self = hs2[(size_t)n * 64 + lane];
    float ax = bflo(self), ay = bfhi(self);
    gather_accum(hs2, csr, off[n], off[n + 1], lane, ax, ay);

    float di = dinv[n];
    float2 bb = ((const float2*)bias)[lane];
    uint rx = f2bf(fmaxf(fmaf(ax, di, bb.x), 0.f));
    uint ry = f2bf(fmaxf(fmaf(ay, di, bb.y), 0.f));
    ((uint*)out)[(size_t)n * 64 + lane] = rx | (ry << 16);
}

// ---------------------------------------------------------------------------
// gather1 + output head fused: compute c1 row in regs, emit out[n] directly
// ---------------------------------------------------------------------------
__global__ void __launch_bounds__(256)
k_gather_out(const ushort* __restrict__ hs, const int* __restrict__ csr,
             const int* __restrict__ off, const float* __restrict__ dinv,
             const float* __restrict__ bias, const ushort* __restrict__ h,
             const ushort* __restrict__ c0, const float* __restrict__ Wout,
             const float* __restrict__ bout, float* __restrict__ out) {
    const int wid = threadIdx.x >> 6;
    const int lane = threadIdx.x & 63;
    const int n = blockIdx.x * 4 + wid;
    if (n >= M_NODES) return;

    const uint* hs2 = (const uint*)hs;
    uint self = hs2[(size_t)n * 64 + lane];
    float ax = bflo(self), ay = bfhi(self);
    gather_accum(hs2, csr, off[n], off[n + 1], lane, ax, ay);

    float di = dinv[n];
    float2 bb = ((const float2*)bias)[lane];
    float cx = fmaxf(fmaf(ax, di, bb.x), 0.f);   // c1[n][2*lane]   (fp32)
    float cy = fmaxf(fmaf(ay, di, bb.y), 0.f);   // c1[n][2*lane+1]

    size_t base = (size_t)n * 64;
    uint a = ((const uint*)h)[base + lane];
    uint b2 = ((const uint*)c0)[base + lane];
    int ch = lane * 2;
    float v = bflo(a) * Wout[ch]        + bfhi(a) * Wout[ch + 1] +
              bflo(b2) * Wout[128 + ch] + bfhi(b2) * Wout[128 + ch + 1] +
              cx * Wout[256 + ch]       + cy * Wout[256 + ch + 1];
#pragma unroll
    for (int o = 32; o; o >>= 1) v += __shfl_down(v, o);
    if (lane == 0) out[n] = v + bout[0];
}

// ---------------------------------------------------------------------------
extern "C" void kernel_launch(void* const* d_in, const int* in_sizes, int n_in,
                              void* d_out, int out_size, void* d_ws, size_t ws_size,
                              hipStream_t stream) {
    const float* x     = (const float*)d_in[0];
    const int*   eidx  = (const int*)d_in[1];
    const float* W_in  = (const float*)d_in[2];
    const float* b_in  = (const float*)d_in[3];
    const float* W_c0  = (const float*)d_in[4];
    const float* b_c0  = (const float*)d_in[5];
    const float* W_c1  = (const float*)d_in[6];
    const float* b_c1  = (const float*)d_in[7];
    const float* W_out = (const float*)d_in[8];
    const float* b_out = (const float*)d_in[9];
    float* out = (float*)d_out;

    const int* src = eidx;
    const int* dst = eidx + N_EDGES;

    // workspace layout (4-byte units)
    float*  ws     = (float*)d_ws;
    float*  dinv   = ws;                            // 100352
    int*    cnt    = (int*)(ws + 100352);           // 100352
    int*    off    = (int*)(ws + 200704);           // 100352 (N+1 used)
    int*    bsum   = (int*)(ws + 301056);           // 128
    int*    csr    = (int*)(ws + 301184);           // 1600000
    ushort* Wt_in  = (ushort*)(ws + 1901184);       // 32768 bf16
    ushort* Wt_c0  = (ushort*)(ws + 1917568);       // 16384 bf16
    ushort* Wt_c1  = (ushort*)(ws + 1925760);       // 16384 bf16
    ushort* h      = (ushort*)(ws + 1933952);       // 12.8M bf16
    ushort* c0     = (ushort*)(ws + 8333952);
    ushort* rank   = (ushort*)(ws + 14733952);      // 1.6M
    ushort* hs     = (ushort*)(ws + 21133952);

    // zero degree counters (graph-capture-safe async memset)
    hipMemsetAsync(cnt, 0, M_NODES * sizeof(int), stream);

    // weight prep || count+rank (LDS-free -> full occupancy)
    k_prep_count<<<256 + CNT_B, 256, 0, stream>>>(W_in, W_c0, W_c1,
                                                  Wt_in, Wt_c0, Wt_c1,
                                                  dst, cnt, rank);

    // scan: cnt -> off, dinv
    k_scanA<<<SCAN_NB, 256, 0, stream>>>(cnt, bsum);
    k_scanB<<<1, 128, 0, stream>>>(bsum, off);
    k_scanC<<<SCAN_NB, 256, 0, stream>>>(cnt, bsum, off, dinv);

    // CSR fill (atomic-free, LDS-free, 8-way MLP)
    k_fill<<<FILL_B, 256, 0, stream>>>(src, dst, off, rank, csr);

    // input layer: h = bf16(relu(x @ W_in + b_in))
    k_gemm<256, 0, true><<<GB, 256, 0, stream>>>(x, Wt_in, b_in, nullptr, h);

    // conv0
    k_gemm<128, 1, false><<<GB, 256, 0, stream>>>(h, Wt_c0, nullptr, dinv, hs);
    k_gather<<<(M_NODES + 3) / 4, 256, 0, stream>>>(hs, csr, off, dinv, b_c0, c0);

    // conv1
    k_gemm<128, 1, false><<<GB, 256, 0, stream>>>(c0, Wt_c1, nullptr, dinv, hs);

    // conv1 aggregate + output head (fused)
    k_gather_out<<<(M_NODES + 3) / 4, 256, 0, stream>>>(hs, csr, off, dinv, b_c1,
                                                        h, c0, W_out, b_out, out);
}

// Round 9
// 299.711 us; speedup vs baseline: 1.0857x; 1.0857x over previous
//
#include <hip/hip_runtime.h>
#include <hip/hip_bf16.h>

#define M_NODES 100000
#define N_EDGES 1600000
#define SCAN_NB 98    // ceil(100000 / 1024)
#define GB 1563       // gemm blocks: ceil(100000/64)
#define CNT_B 1024    // count blocks (8 edges/thread)
#define FILL_B 1024   // fill blocks (8 edges/thread)

typedef __attribute__((ext_vector_type(8))) short short8;
typedef __attribute__((ext_vector_type(4))) float f32x4;
typedef __attribute__((ext_vector_type(2))) float f32x2;
typedef __attribute__((address_space(3))) void lds_t;
typedef const __attribute__((address_space(1))) void gld_t;

__device__ __forceinline__ ushort f2bf(float f) {
    union { float f; uint u; } x; x.f = f;
    uint r = x.u + 0x7fffu + ((x.u >> 16) & 1u);   // RNE
    return (ushort)(r >> 16);
}
__device__ __forceinline__ float bflo(uint v) {
    union { uint u; float f; } x; x.u = v << 16; return x.f;
}
__device__ __forceinline__ float bfhi(uint v) {
    union { uint u; float f; } x; x.u = v & 0xffff0000u; return x.f;
}

// ---------------------------------------------------------------------------
// fused weight prep (transpose+bf16)  ||  degree count + rank (LDS-free)
// blocks 0..127: Wt_in; 128..191: Wt_c0; 192..255: Wt_c1; 256..: count
// cnt must be zeroed beforehand (hipMemsetAsync).
// ---------------------------------------------------------------------------
__global__ void __launch_bounds__(256)
k_prep_count(const float* __restrict__ W_in, const float* __restrict__ W_c0,
             const float* __restrict__ W_c1, ushort* __restrict__ Wt_in,
             ushort* __restrict__ Wt_c0, ushort* __restrict__ Wt_c1,
             const int* __restrict__ dst, int* __restrict__ cnt,
             ushort* __restrict__ rank) {
    const int b = blockIdx.x, t = threadIdx.x;
    if (b < 128) {
        int i = b * 256 + t;              // c = i>>8, k = i&255
        Wt_in[i] = f2bf(W_in[(size_t)(i & 255) * 128 + (i >> 8)]);
    } else if (b < 192) {
        int i = (b - 128) * 256 + t;      // c = i>>7, k = i&127
        Wt_c0[i] = f2bf(W_c0[(size_t)(i & 127) * 128 + (i >> 7)]);
    } else if (b < 256) {
        int i = (b - 192) * 256 + t;
        Wt_c1[i] = f2bf(W_c1[(size_t)(i & 127) * 128 + (i >> 7)]);
    } else {
        // count: 8 edges/thread, independent atomic chains (MLP=8)
        const int base = (b - 256) * 2048 + t;
        int d[8]; bool ok[8]; int r[8];
#pragma unroll
        for (int i = 0; i < 8; ++i) {
            int e = base + i * 256;
            ok[i] = e < N_EDGES;
            d[i] = ok[i] ? dst[e] : 0;
        }
#pragma unroll
        for (int i = 0; i < 8; ++i)
            if (ok[i]) r[i] = atomicAdd(&cnt[d[i]], 1);
#pragma unroll
        for (int i = 0; i < 8; ++i)
            if (ok[i]) rank[base + i * 256] = (ushort)r[i];
    }
}

// ---------------------------------------------------------------------------
// 3-phase exclusive scan (off) + dinv
// ---------------------------------------------------------------------------
__global__ void __launch_bounds__(256)
k_scanA(const int* __restrict__ cnt, int* __restrict__ bsum) {
    __shared__ int sh[256];
    const int b = blockIdx.x, t = threadIdx.x;
    int base = b * 1024 + t * 4;
    int s = 0;
#pragma unroll
    for (int j = 0; j < 4; ++j) {
        int i = base + j;
        if (i < M_NODES) s += cnt[i];
    }
    sh[t] = s;
    __syncthreads();
    for (int o = 128; o; o >>= 1) {
        if (t < o) sh[t] += sh[t + o];
        __syncthreads();
    }
    if (t == 0) bsum[b] = sh[0];
}

__global__ void __launch_bounds__(128)
k_scanB(int* __restrict__ bsum, int* __restrict__ off) {
    __shared__ int sh[128];
    const int t = threadIdx.x;
    int v = (t < SCAN_NB) ? bsum[t] : 0;
    sh[t] = v;
    __syncthreads();
    for (int o = 1; o < 128; o <<= 1) {
        int u = (t >= o) ? sh[t - o] : 0;
        __syncthreads();
        sh[t] += u;
        __syncthreads();
    }
    if (t < SCAN_NB) bsum[t] = sh[t] - v;  // exclusive
    if (t == 0) off[M_NODES] = N_EDGES;
}

__global__ void __launch_bounds__(256)
k_scanC(const int* __restrict__ cnt, const int* __restrict__ bsum,
        int* __restrict__ off, float* __restrict__ dinv) {
    __shared__ int sh[256];
    const int b = blockIdx.x, t = threadIdx.x;
    int base = b * 1024 + t * 4;
    int loc[4];
    int s = 0;
#pragma unroll
    for (int j = 0; j < 4; ++j) {
        int i = base + j;
        loc[j] = (i < M_NODES) ? cnt[i] : 0;
        s += loc[j];
    }
    sh[t] = s;
    __syncthreads();
    for (int o = 1; o < 256; o <<= 1) {
        int u = (t >= o) ? sh[t - o] : 0;
        __syncthreads();
        sh[t] += u;
        __syncthreads();
    }
    int run = bsum[b] + sh[t] - s;
#pragma unroll
    for (int j = 0; j < 4; ++j) {
        int i = base + j;
        if (i < M_NODES) {
            off[i] = run;
            dinv[i] = rsqrtf((float)(loc[j] + 1));
            run += loc[j];
        }
    }
}

// ---------------------------------------------------------------------------
// atomic-free CSR fill, LDS-free, 8 edges/thread
// ---------------------------------------------------------------------------
__global__ void __launch_bounds__(256)
k_fill(const int* __restrict__ src, const int* __restrict__ dst,
       const int* __restrict__ off, const ushort* __restrict__ rank,
       int* __restrict__ csr) {
    const int base = blockIdx.x * 2048 + threadIdx.x;
    int d[8], s[8]; ushort r[8]; bool ok[8]; int o[8];
#pragma unroll
    for (int i = 0; i < 8; ++i) {
        int e = base + i * 256;
        ok[i] = e < N_EDGES;
        d[i] = ok[i] ? dst[e] : 0;
        s[i] = ok[i] ? src[e] : 0;
        r[i] = ok[i] ? rank[e] : 0;
    }
#pragma unroll
    for (int i = 0; i < 8; ++i) o[i] = ok[i] ? off[d[i]] : 0;
#pragma unroll
    for (int i = 0; i < 8; ++i)
        if (ok[i]) csr[o[i] + (int)r[i]] = s[i];
}

// ---------------------------------------------------------------------------
// MFMA GEMM: A[M,K] @ B[K,128], Bt[128][K] bf16.
// 64x128 tile, BK=64, 4 waves (2x2): wave = 32 rows x 64 cols, 2x4 frags.
// MODE 0: out = bf16(relu(A@B + bias));  MODE 1: out = bf16((A@B)*dinv[row])
// ---------------------------------------------------------------------------
template <int K, int MODE, bool AF32>
__global__ void __launch_bounds__(256)
k_gemm(const void* __restrict__ Av, const ushort* __restrict__ Bt,
       const float* __restrict__ bias, const float* __restrict__ dinv,
       ushort* __restrict__ out) {
    __shared__ ushort As[64 * 64];    // [row][k] 8 KB
    __shared__ ushort Bs[128 * 64];   // [col][k] 16 KB
    const int t = threadIdx.x;
    const int lane = t & 63, w = t >> 6;
    const int wr = w >> 1, wc = w & 1;
    const int l15 = lane & 15, l4 = lane >> 4;
    const int row0 = blockIdx.x * 64;

    f32x4 acc[2][4] = {};

    for (int k0 = 0; k0 < K; k0 += 64) {
#pragma unroll
        for (int i = 0; i < 4; ++i) {
            int idx = (i * 256 + t) * 8;          // bf16 elem index in tile
            int col = idx >> 6, kc = idx & 63;
            __builtin_amdgcn_global_load_lds(
                (gld_t*)(Bt + (size_t)col * K + k0 + kc),
                (lds_t*)(Bs + idx), 16, 0, 0);
        }
        if (AF32) {
            const float* A = (const float*)Av;
#pragma unroll
            for (int i = 0; i < 2; ++i) {
                int idx = (i * 256 + t) * 8;
                int r = idx >> 6, c = idx & 63;
                int gr = row0 + r; gr = gr < M_NODES ? gr : M_NODES - 1;
                const float4* gp = (const float4*)(A + (size_t)gr * K + k0 + c);
                float4 v0 = gp[0], v1 = gp[1];
                short8 p;
                p[0] = (short)f2bf(v0.x); p[1] = (short)f2bf(v0.y);
                p[2] = (short)f2bf(v0.z); p[3] = (short)f2bf(v0.w);
                p[4] = (short)f2bf(v1.x); p[5] = (short)f2bf(v1.y);
                p[6] = (short)f2bf(v1.z); p[7] = (short)f2bf(v1.w);
                *reinterpret_cast<short8*>(&As[idx]) = p;
            }
        } else {
            const ushort* A = (const ushort*)Av;
#pragma unroll
            for (int i = 0; i < 2; ++i) {
                int idx = (i * 256 + t) * 8;
                int r = idx >> 6, c = idx & 63;
                int gr = row0 + r; gr = gr < M_NODES ? gr : M_NODES - 1;
                __builtin_amdgcn_global_load_lds(
                    (gld_t*)(A + (size_t)gr * K + k0 + c),
                    (lds_t*)(As + idx), 16, 0, 0);
            }
        }
        __syncthreads();
#pragma unroll
        for (int kk = 0; kk < 2; ++kk) {
            short8 af[2], bw[4];
#pragma unroll
            for (int m = 0; m < 2; ++m)
                af[m] = *reinterpret_cast<const short8*>(
                    &As[(wr * 32 + m * 16 + l15) * 64 + kk * 32 + l4 * 8]);
#pragma unroll
            for (int n = 0; n < 4; ++n)
                bw[n] = *reinterpret_cast<const short8*>(
                    &Bs[(wc * 64 + n * 16 + l15) * 64 + kk * 32 + l4 * 8]);
#pragma unroll
            for (int m = 0; m < 2; ++m)
#pragma unroll
                for (int n = 0; n < 4; ++n)
                    acc[m][n] = __builtin_amdgcn_mfma_f32_16x16x32_bf16(
                        af[m], bw[n], acc[m][n], 0, 0, 0);
        }
        __syncthreads();
    }

    // epilogue: C[row][col], col = lane&15, row = (lane>>4)*4 + j
#pragma unroll
    for (int m = 0; m < 2; ++m) {
#pragma unroll
        for (int j = 0; j < 4; ++j) {
            int r = row0 + wr * 32 + m * 16 + l4 * 4 + j;
            if (r < M_NODES) {
                float sc = (MODE == 1) ? dinv[r] : 0.f;
#pragma unroll
                for (int n = 0; n < 4; ++n) {
                    int c = wc * 64 + n * 16 + l15;
                    float v = acc[m][n][j];
                    if (MODE == 0) v = fmaxf(v + bias[c], 0.f);
                    else v *= sc;
                    out[(size_t)r * 128 + c] = f2bf(v);
                }
            }
        }
    }
}

// ---------------------------------------------------------------------------
// neighbor accumulation core: readlane -> uniform SGPR row base (SALU addr,
// saddr-form loads with loop-invariant lane voffset), 8 loads in flight,
// f32x2 accumulators (v_pk_add_f32 candidate). All acc indices static.
// ---------------------------------------------------------------------------
__device__ __forceinline__ void
gather_accum(const uint* __restrict__ hs2, const int* __restrict__ csr,
             int beg, int end, int lane, float& ax, float& ay) {
    f32x2 acc[8] = {};
    for (int b = beg; b < end; b += 64) {
        int m = end - b; if (m > 64) m = 64;
        int idx = (lane < m) ? csr[b + lane] : 0;
        int i = 0;
        for (; i + 8 <= m; i += 8) {
            const uint* r0 = hs2 + ((size_t)(uint)__builtin_amdgcn_readlane(idx, i + 0) << 6);
            const uint* r1 = hs2 + ((size_t)(uint)__builtin_amdgcn_readlane(idx, i + 1) << 6);
            const uint* r2 = hs2 + ((size_t)(uint)__builtin_amdgcn_readlane(idx, i + 2) << 6);
            const uint* r3 = hs2 + ((size_t)(uint)__builtin_amdgcn_readlane(idx, i + 3) << 6);
            const uint* r4 = hs2 + ((size_t)(uint)__builtin_amdgcn_readlane(idx, i + 4) << 6);
            const uint* r5 = hs2 + ((size_t)(uint)__builtin_amdgcn_readlane(idx, i + 5) << 6);
            const uint* r6 = hs2 + ((size_t)(uint)__builtin_amdgcn_readlane(idx, i + 6) << 6);
            const uint* r7 = hs2 + ((size_t)(uint)__builtin_amdgcn_readlane(idx, i + 7) << 6);
            uint v0 = r0[lane], v1 = r1[lane], v2 = r2[lane], v3 = r3[lane];
            uint v4 = r4[lane], v5 = r5[lane], v6 = r6[lane], v7 = r7[lane];
            acc[0] += (f32x2){bflo(v0), bfhi(v0)};
            acc[1] += (f32x2){bflo(v1), bfhi(v1)};
            acc[2] += (f32x2){bflo(v2), bfhi(v2)};
            acc[3] += (f32x2){bflo(v3), bfhi(v3)};
            acc[4] += (f32x2){bflo(v4), bfhi(v4)};
            acc[5] += (f32x2){bflo(v5), bfhi(v5)};
            acc[6] += (f32x2){bflo(v6), bfhi(v6)};
            acc[7] += (f32x2){bflo(v7), bfhi(v7)};
        }
        // tail <= 7: static unroll, uniform guards, static acc indices
#pragma unroll
        for (int k = 0; k < 7; ++k) {
            if (i + k < m) {
                const uint* r = hs2 + ((size_t)(uint)__builtin_amdgcn_readlane(idx, i + k) << 6);
                uint v = r[lane];
                acc[k] += (f32x2){bflo(v), bfhi(v)};
            }
        }
    }
    f32x2 s = ((acc[0] + acc[1]) + (acc[2] + acc[3])) +
              ((acc[4] + acc[5]) + (acc[6] + acc[7]));
    ax += s.x;
    ay += s.y;
}

// ---------------------------------------------------------------------------
// gather-aggregate (bf16): one wave per node, uint (2 bf16) per lane
// ---------------------------------------------------------------------------
__global__ void __launch_bounds__(256)
k_gather(const ushort* __restrict__ hs, const int* __restrict__ csr,
         const int* __restrict__ off, const float* __restrict__ dinv,
         const float* __restrict__ bias, ushort* __restrict__ out) {
    const int wid = threadIdx.x >> 6;
    const int lane = threadIdx.x & 63;
    const int n = blockIdx.x * 4 + wid;
    if (n >= M_NODES) return;

    const uint* hs2 = (const uint*)hs;
    uint self = hs2[(size_t)n * 64 + lane];
    float ax = bflo(self), ay = bfhi(self);
    gather_accum(hs2, csr, off[n], off[n + 1], lane, ax, ay);

    float di = dinv[n];
    float2 bb = ((const float2*)bias)[lane];
    uint rx = f2bf(fmaxf(fmaf(ax, di, bb.x), 0.f));
    uint ry = f2bf(fmaxf(fmaf(ay, di, bb.y), 0.f));
    ((uint*)out)[(size_t)n * 64 + lane] = rx | (ry << 16);
}

// ---------------------------------------------------------------------------
// gather1 + output head fused: compute c1 row in regs, emit out[n] directly
// ---------------------------------------------------------------------------
__global__ void __launch_bounds__(256)
k_gather_out(const ushort* __restrict__ hs, const int* __restrict__ csr,
             const int* __restrict__ off, const float* __restrict__ dinv,
             const float* __restrict__ bias, const ushort* __restrict__ h,
             const ushort* __restrict__ c0, const float* __restrict__ Wout,
             const float* __restrict__ bout, float* __restrict__ out) {
    const int wid = threadIdx.x >> 6;
    const int lane = threadIdx.x & 63;
    const int n = blockIdx.x * 4 + wid;
    if (n >= M_NODES) return;

    const uint* hs2 = (const uint*)hs;
    uint self = hs2[(size_t)n * 64 + lane];
    float ax = bflo(self), ay = bfhi(self);
    gather_accum(hs2, csr, off[n], off[n + 1], lane, ax, ay);

    float di = dinv[n];
    float2 bb = ((const float2*)bias)[lane];
    float cx = fmaxf(fmaf(ax, di, bb.x), 0.f);   // c1[n][2*lane]   (fp32)
    float cy = fmaxf(fmaf(ay, di, bb.y), 0.f);   // c1[n][2*lane+1]

    size_t base = (size_t)n * 64;
    uint a = ((const uint*)h)[base + lane];
    uint b2 = ((const uint*)c0)[base + lane];
    int ch = lane * 2;
    float v = bflo(a) * Wout[ch]        + bfhi(a) * Wout[ch + 1] +
              bflo(b2) * Wout[128 + ch] + bfhi(b2) * Wout[128 + ch + 1] +
              cx * Wout[256 + ch]       + cy * Wout[256 + ch + 1];
#pragma unroll
    for (int o = 32; o; o >>= 1) v += __shfl_down(v, o);
    if (lane == 0) out[n] = v + bout[0];
}

// ---------------------------------------------------------------------------
extern "C" void kernel_launch(void* const* d_in, const int* in_sizes, int n_in,
                              void* d_out, int out_size, void* d_ws, size_t ws_size,
                              hipStream_t stream) {
    const float* x     = (const float*)d_in[0];
    const int*   eidx  = (const int*)d_in[1];
    const float* W_in  = (const float*)d_in[2];
    const float* b_in  = (const float*)d_in[3];
    const float* W_c0  = (const float*)d_in[4];
    const float* b_c0  = (const float*)d_in[5];
    const float* W_c1  = (const float*)d_in[6];
    const float* b_c1  = (const float*)d_in[7];
    const float* W_out = (const float*)d_in[8];
    const float* b_out = (const float*)d_in[9];
    float* out = (float*)d_out;

    const int* src = eidx;
    const int* dst = eidx + N_EDGES;

    // workspace layout (4-byte units)
    float*  ws     = (float*)d_ws;
    float*  dinv   = ws;                            // 100352
    int*    cnt    = (int*)(ws + 100352);           // 100352
    int*    off    = (int*)(ws + 200704);           // 100352 (N+1 used)
    int*    bsum   = (int*)(ws + 301056);           // 128
    int*    csr    = (int*)(ws + 301184);           // 1600000
    ushort* Wt_in  = (ushort*)(ws + 1901184);       // 32768 bf16
    ushort* Wt_c0  = (ushort*)(ws + 1917568);       // 16384 bf16
    ushort* Wt_c1  = (ushort*)(ws + 1925760);       // 16384 bf16
    ushort* h      = (ushort*)(ws + 1933952);       // 12.8M bf16
    ushort* c0     = (ushort*)(ws + 8333952);
    ushort* rank   = (ushort*)(ws + 14733952);      // 1.6M
    ushort* hs     = (ushort*)(ws + 21133952);

    // zero degree counters (graph-capture-safe async memset)
    hipMemsetAsync(cnt, 0, M_NODES * sizeof(int), stream);

    // weight prep || count+rank (LDS-free -> full occupancy)
    k_prep_count<<<256 + CNT_B, 256, 0, stream>>>(W_in, W_c0, W_c1,
                                                  Wt_in, Wt_c0, Wt_c1,
                                                  dst, cnt, rank);

    // scan: cnt -> off, dinv
    k_scanA<<<SCAN_NB, 256, 0, stream>>>(cnt, bsum);
    k_scanB<<<1, 128, 0, stream>>>(bsum, off);
    k_scanC<<<SCAN_NB, 256, 0, stream>>>(cnt, bsum, off, dinv);

    // CSR fill (atomic-free, LDS-free, 8-way MLP)
    k_fill<<<FILL_B, 256, 0, stream>>>(src, dst, off, rank, csr);

    // input layer: h = bf16(relu(x @ W_in + b_in))
    k_gemm<256, 0, true><<<GB, 256, 0, stream>>>(x, Wt_in, b_in, nullptr, h);

    // conv0
    k_gemm<128, 1, false><<<GB, 256, 0, stream>>>(h, Wt_c0, nullptr, dinv, hs);
    k_gather<<<(M_NODES + 3) / 4, 256, 0, stream>>>(hs, csr, off, dinv, b_c0, c0);

    // conv1
    k_gemm<128, 1, false><<<GB, 256, 0, stream>>>(c0, Wt_c1, nullptr, dinv, hs);

    // conv1 aggregate + output head (fused)
    k_gather_out<<<(M_NODES + 3) / 4, 256, 0, stream>>>(hs, csr, off, dinv, b_c1,
                                                        h, c0, W_out, b_out, out);
}

// Round 10
// 283.133 us; speedup vs baseline: 1.1493x; 1.0586x over previous
//
#include <hip/hip_runtime.h>
#include <hip/hip_bf16.h>

#define M_NODES 100000
#define N_EDGES 1600000
#define SCAN_NB 98    // ceil(100000 / 1024)
#define GB 1563       // gemm blocks: ceil(100000/64); also edge-slice owner blocks

typedef __attribute__((ext_vector_type(8))) short short8;
typedef __attribute__((ext_vector_type(4))) float f32x4;
typedef __attribute__((ext_vector_type(2))) float f32x2;
typedef __attribute__((address_space(3))) void lds_t;
typedef const __attribute__((address_space(1))) void gld_t;

__device__ __forceinline__ ushort f2bf(float f) {
    union { float f; uint u; } x; x.f = f;
    uint r = x.u + 0x7fffu + ((x.u >> 16) & 1u);   // RNE
    return (ushort)(r >> 16);
}
__device__ __forceinline__ float bflo(uint v) {
    union { uint u; float f; } x; x.u = v << 16; return x.f;
}
__device__ __forceinline__ float bfhi(uint v) {
    union { uint u; float f; } x; x.u = v & 0xffff0000u; return x.f;
}

// ---------------------------------------------------------------------------
// weight prep (transpose + bf16), tiny standalone
// ---------------------------------------------------------------------------
__global__ void __launch_bounds__(256)
k_prep(const float* __restrict__ W_in, const float* __restrict__ W_c0,
       const float* __restrict__ W_c1, ushort* __restrict__ Wt_in,
       ushort* __restrict__ Wt_c0, ushort* __restrict__ Wt_c1) {
    const int b = blockIdx.x, t = threadIdx.x;
    if (b < 128) {
        int i = b * 256 + t;              // c = i>>8, k = i&255
        Wt_in[i] = f2bf(W_in[(size_t)(i & 255) * 128 + (i >> 8)]);
    } else if (b < 192) {
        int i = (b - 128) * 256 + t;      // c = i>>7, k = i&127
        Wt_c0[i] = f2bf(W_c0[(size_t)(i & 127) * 128 + (i >> 7)]);
    } else {
        int i = (b - 192) * 256 + t;
        Wt_c1[i] = f2bf(W_c1[(size_t)(i & 127) * 128 + (i >> 7)]);
    }
}

// ---------------------------------------------------------------------------
// 3-phase exclusive scan (off) + dinv
// ---------------------------------------------------------------------------
__global__ void __launch_bounds__(256)
k_scanA(const int* __restrict__ cnt, int* __restrict__ bsum) {
    __shared__ int sh[256];
    const int b = blockIdx.x, t = threadIdx.x;
    int base = b * 1024 + t * 4;
    int s = 0;
#pragma unroll
    for (int j = 0; j < 4; ++j) {
        int i = base + j;
        if (i < M_NODES) s += cnt[i];
    }
    sh[t] = s;
    __syncthreads();
    for (int o = 128; o; o >>= 1) {
        if (t < o) sh[t] += sh[t + o];
        __syncthreads();
    }
    if (t == 0) bsum[b] = sh[0];
}

__global__ void __launch_bounds__(128)
k_scanB(int* __restrict__ bsum, int* __restrict__ off) {
    __shared__ int sh[128];
    const int t = threadIdx.x;
    int v = (t < SCAN_NB) ? bsum[t] : 0;
    sh[t] = v;
    __syncthreads();
    for (int o = 1; o < 128; o <<= 1) {
        int u = (t >= o) ? sh[t - o] : 0;
        __syncthreads();
        sh[t] += u;
        __syncthreads();
    }
    if (t < SCAN_NB) bsum[t] = sh[t] - v;  // exclusive
    if (t == 0) off[M_NODES] = N_EDGES;
}

__global__ void __launch_bounds__(256)
k_scanC(const int* __restrict__ cnt, const int* __restrict__ bsum,
        int* __restrict__ off, float* __restrict__ dinv) {
    __shared__ int sh[256];
    const int b = blockIdx.x, t = threadIdx.x;
    int base = b * 1024 + t * 4;
    int loc[4];
    int s = 0;
#pragma unroll
    for (int j = 0; j < 4; ++j) {
        int i = base + j;
        loc[j] = (i < M_NODES) ? cnt[i] : 0;
        s += loc[j];
    }
    sh[t] = s;
    __syncthreads();
    for (int o = 1; o < 256; o <<= 1) {
        int u = (t >= o) ? sh[t - o] : 0;
        __syncthreads();
        sh[t] += u;
        __syncthreads();
    }
    int run = bsum[b] + sh[t] - s;
#pragma unroll
    for (int j = 0; j < 4; ++j) {
        int i = base + j;
        if (i < M_NODES) {
            off[i] = run;
            dinv[i] = rsqrtf((float)(loc[j] + 1));
            run += loc[j];
        }
    }
}

// ---------------------------------------------------------------------------
// MFMA GEMM body: A[M,K] @ B[K,128], Bt[128][K] bf16.
// 64x128 tile, BK=64, 4 waves (2x2): wave = 32 rows x 64 cols, 2x4 frags.
// MODE 0: out = bf16(relu(A@B + bias));  MODE 1: out = bf16((A@B)*dinv[row])
// ---------------------------------------------------------------------------
template <int K, int MODE, bool AF32>
__device__ __forceinline__ void
gemm_body(int bid, const void* __restrict__ Av, const ushort* __restrict__ Bt,
          const float* __restrict__ bias, const float* __restrict__ dinv,
          ushort* __restrict__ out) {
    __shared__ ushort As[64 * 64];    // [row][k] 8 KB
    __shared__ ushort Bs[128 * 64];   // [col][k] 16 KB
    const int t = threadIdx.x;
    const int lane = t & 63, w = t >> 6;
    const int wr = w >> 1, wc = w & 1;
    const int l15 = lane & 15, l4 = lane >> 4;
    const int row0 = bid * 64;

    f32x4 acc[2][4] = {};

    for (int k0 = 0; k0 < K; k0 += 64) {
#pragma unroll
        for (int i = 0; i < 4; ++i) {
            int idx = (i * 256 + t) * 8;          // bf16 elem index in tile
            int col = idx >> 6, kc = idx & 63;
            __builtin_amdgcn_global_load_lds(
                (gld_t*)(Bt + (size_t)col * K + k0 + kc),
                (lds_t*)(Bs + idx), 16, 0, 0);
        }
        if (AF32) {
            const float* A = (const float*)Av;
#pragma unroll
            for (int i = 0; i < 2; ++i) {
                int idx = (i * 256 + t) * 8;
                int r = idx >> 6, c = idx & 63;
                int gr = row0 + r; gr = gr < M_NODES ? gr : M_NODES - 1;
                const float4* gp = (const float4*)(A + (size_t)gr * K + k0 + c);
                float4 v0 = gp[0], v1 = gp[1];
                short8 p;
                p[0] = (short)f2bf(v0.x); p[1] = (short)f2bf(v0.y);
                p[2] = (short)f2bf(v0.z); p[3] = (short)f2bf(v0.w);
                p[4] = (short)f2bf(v1.x); p[5] = (short)f2bf(v1.y);
                p[6] = (short)f2bf(v1.z); p[7] = (short)f2bf(v1.w);
                *reinterpret_cast<short8*>(&As[idx]) = p;
            }
        } else {
            const ushort* A = (const ushort*)Av;
#pragma unroll
            for (int i = 0; i < 2; ++i) {
                int idx = (i * 256 + t) * 8;
                int r = idx >> 6, c = idx & 63;
                int gr = row0 + r; gr = gr < M_NODES ? gr : M_NODES - 1;
                __builtin_amdgcn_global_load_lds(
                    (gld_t*)(A + (size_t)gr * K + k0 + c),
                    (lds_t*)(As + idx), 16, 0, 0);
            }
        }
        __syncthreads();
#pragma unroll
        for (int kk = 0; kk < 2; ++kk) {
            short8 af[2], bw[4];
#pragma unroll
            for (int m = 0; m < 2; ++m)
                af[m] = *reinterpret_cast<const short8*>(
                    &As[(wr * 32 + m * 16 + l15) * 64 + kk * 32 + l4 * 8]);
#pragma unroll
            for (int n = 0; n < 4; ++n)
                bw[n] = *reinterpret_cast<const short8*>(
                    &Bs[(wc * 64 + n * 16 + l15) * 64 + kk * 32 + l4 * 8]);
#pragma unroll
            for (int m = 0; m < 2; ++m)
#pragma unroll
                for (int n = 0; n < 4; ++n)
                    acc[m][n] = __builtin_amdgcn_mfma_f32_16x16x32_bf16(
                        af[m], bw[n], acc[m][n], 0, 0, 0);
        }
        __syncthreads();
    }

    // epilogue: C[row][col], col = lane&15, row = (lane>>4)*4 + j
#pragma unroll
    for (int m = 0; m < 2; ++m) {
#pragma unroll
        for (int j = 0; j < 4; ++j) {
            int r = row0 + wr * 32 + m * 16 + l4 * 4 + j;
            if (r < M_NODES) {
                float sc = (MODE == 1) ? dinv[r] : 0.f;
#pragma unroll
                for (int n = 0; n < 4; ++n) {
                    int c = wc * 64 + n * 16 + l15;
                    float v = acc[m][n][j];
                    if (MODE == 0) v = fmaxf(v + bias[c], 0.f);
                    else v *= sc;
                    out[(size_t)r * 128 + c] = f2bf(v);
                }
            }
        }
    }
}

// ---------------------------------------------------------------------------
// phase 1: every block does its input-GEMM tile, THEN its own slice of
// count+rank (4 edges/thread). Edge work runs at GEMM occupancy and its
// atomic latency overlaps the grid's staggered tail.
// cnt must be zeroed beforehand (hipMemsetAsync).
// ---------------------------------------------------------------------------
__global__ void __launch_bounds__(256)
k_phase1(const float* __restrict__ x, const ushort* __restrict__ Wt_in,
         const float* __restrict__ b_in, ushort* __restrict__ h,
         const int* __restrict__ dst, int* __restrict__ cnt,
         ushort* __restrict__ rank) {
    gemm_body<256, 0, true>(blockIdx.x, x, Wt_in, b_in, nullptr, h);

    // count slice: GB*1024 = 1,600,512 slots >= N_EDGES
    const int base = blockIdx.x * 1024 + threadIdx.x;
    int d[4]; bool ok[4]; int r[4];
#pragma unroll
    for (int i = 0; i < 4; ++i) {
        int e = base + i * 256;
        ok[i] = e < N_EDGES;
        d[i] = ok[i] ? dst[e] : 0;
    }
#pragma unroll
    for (int i = 0; i < 4; ++i)
        if (ok[i]) r[i] = atomicAdd(&cnt[d[i]], 1);
#pragma unroll
    for (int i = 0; i < 4; ++i)
        if (ok[i]) rank[base + i * 256] = (ushort)r[i];
}

// ---------------------------------------------------------------------------
// phase 3: every block does its conv0-GEMM tile, THEN its own slice of the
// atomic-free CSR fill (4 edges/thread).
// ---------------------------------------------------------------------------
__global__ void __launch_bounds__(256)
k_phase3(const ushort* __restrict__ h, const ushort* __restrict__ Wt_c0,
         const float* __restrict__ dinv, ushort* __restrict__ hs,
         const int* __restrict__ src, const int* __restrict__ dst,
         const int* __restrict__ off, const ushort* __restrict__ rank,
         int* __restrict__ csr) {
    gemm_body<128, 1, false>(blockIdx.x, h, Wt_c0, nullptr, dinv, hs);

    const int base = blockIdx.x * 1024 + threadIdx.x;
    int d[4], s[4]; ushort r[4]; bool ok[4]; int o[4];
#pragma unroll
    for (int i = 0; i < 4; ++i) {
        int e = base + i * 256;
        ok[i] = e < N_EDGES;
        d[i] = ok[i] ? dst[e] : 0;
        s[i] = ok[i] ? src[e] : 0;
        r[i] = ok[i] ? rank[e] : 0;
    }
#pragma unroll
    for (int i = 0; i < 4; ++i) o[i] = ok[i] ? off[d[i]] : 0;
#pragma unroll
    for (int i = 0; i < 4; ++i)
        if (ok[i]) csr[o[i] + (int)r[i]] = s[i];
}

template <int K, int MODE, bool AF32>
__global__ void __launch_bounds__(256)
k_gemm(const void* __restrict__ Av, const ushort* __restrict__ Bt,
       const float* __restrict__ bias, const float* __restrict__ dinv,
       ushort* __restrict__ out) {
    gemm_body<K, MODE, AF32>(blockIdx.x, Av, Bt, bias, dinv, out);
}

// ---------------------------------------------------------------------------
// neighbor accumulation core: readlane -> uniform SGPR row base (SALU addr),
// 8 loads in flight, f32x2 accumulators, static indices only.
// ---------------------------------------------------------------------------
__device__ __forceinline__ void
gather_accum(const uint* __restrict__ hs2, const int* __restrict__ csr,
             int beg, int end, int lane, float& ax, float& ay) {
    f32x2 acc[8] = {};
    for (int b = beg; b < end; b += 64) {
        int m = end - b; if (m > 64) m = 64;
        int idx = (lane < m) ? csr[b + lane] : 0;
        int i = 0;
        for (; i + 8 <= m; i += 8) {
            const uint* r0 = hs2 + ((size_t)(uint)__builtin_amdgcn_readlane(idx, i + 0) << 6);
            const uint* r1 = hs2 + ((size_t)(uint)__builtin_amdgcn_readlane(idx, i + 1) << 6);
            const uint* r2 = hs2 + ((size_t)(uint)__builtin_amdgcn_readlane(idx, i + 2) << 6);
            const uint* r3 = hs2 + ((size_t)(uint)__builtin_amdgcn_readlane(idx, i + 3) << 6);
            const uint* r4 = hs2 + ((size_t)(uint)__builtin_amdgcn_readlane(idx, i + 4) << 6);
            const uint* r5 = hs2 + ((size_t)(uint)__builtin_amdgcn_readlane(idx, i + 5) << 6);
            const uint* r6 = hs2 + ((size_t)(uint)__builtin_amdgcn_readlane(idx, i + 6) << 6);
            const uint* r7 = hs2 + ((size_t)(uint)__builtin_amdgcn_readlane(idx, i + 7) << 6);
            uint v0 = r0[lane], v1 = r1[lane], v2 = r2[lane], v3 = r3[lane];
            uint v4 = r4[lane], v5 = r5[lane], v6 = r6[lane], v7 = r7[lane];
            acc[0] += (f32x2){bflo(v0), bfhi(v0)};
            acc[1] += (f32x2){bflo(v1), bfhi(v1)};
            acc[2] += (f32x2){bflo(v2), bfhi(v2)};
            acc[3] += (f32x2){bflo(v3), bfhi(v3)};
            acc[4] += (f32x2){bflo(v4), bfhi(v4)};
            acc[5] += (f32x2){bflo(v5), bfhi(v5)};
            acc[6] += (f32x2){bflo(v6), bfhi(v6)};
            acc[7] += (f32x2){bflo(v7), bfhi(v7)};
        }
        // tail <= 7: static unroll, uniform guards, static acc indices
#pragma unroll
        for (int k = 0; k < 7; ++k) {
            if (i + k < m) {
                const uint* r = hs2 + ((size_t)(uint)__builtin_amdgcn_readlane(idx, i + k) << 6);
                uint v = r[lane];
                acc[k] += (f32x2){bflo(v), bfhi(v)};
            }
        }
    }
    f32x2 s = ((acc[0] + acc[1]) + (acc[2] + acc[3])) +
              ((acc[4] + acc[5]) + (acc[6] + acc[7]));
    ax += s.x;
    ay += s.y;
}

// ---------------------------------------------------------------------------
// gather-aggregate (bf16): one wave per node, uint (2 bf16) per lane
// ---------------------------------------------------------------------------
__global__ void __launch_bounds__(256)
k_gather(const ushort* __restrict__ hs, const int* __restrict__ csr,
         const int* __restrict__ off, const float* __restrict__ dinv,
         const float* __restrict__ bias, ushort* __restrict__ out) {
    const int wid = threadIdx.x >> 6;
    const int lane = threadIdx.x & 63;
    const int n = blockIdx.x * 4 + wid;
    if (n >= M_NODES) return;

    const uint* hs2 = (const uint*)hs;
    uint self = hs2[(size_t)n * 64 + lane];
    float ax = bflo(self), ay = bfhi(self);
    gather_accum(hs2, csr, off[n], off[n + 1], lane, ax, ay);

    float di = dinv[n];
    float2 bb = ((const float2*)bias)[lane];
    uint rx = f2bf(fmaxf(fmaf(ax, di, bb.x), 0.f));
    uint ry = f2bf(fmaxf(fmaf(ay, di, bb.y), 0.f));
    ((uint*)out)[(size_t)n * 64 + lane] = rx | (ry << 16);
}

// ---------------------------------------------------------------------------
// gather1 + output head fused: compute c1 row in regs, emit out[n] directly
// ---------------------------------------------------------------------------
__global__ void __launch_bounds__(256)
k_gather_out(const ushort* __restrict__ hs, const int* __restrict__ csr,
             const int* __restrict__ off, const float* __restrict__ dinv,
             const float* __restrict__ bias, const ushort* __restrict__ h,
             const ushort* __restrict__ c0, const float* __restrict__ Wout,
             const float* __restrict__ bout, float* __restrict__ out) {
    const int wid = threadIdx.x >> 6;
    const int lane = threadIdx.x & 63;
    const int n = blockIdx.x * 4 + wid;
    if (n >= M_NODES) return;

    const uint* hs2 = (const uint*)hs;
    uint self = hs2[(size_t)n * 64 + lane];
    float ax = bflo(self), ay = bfhi(self);
    gather_accum(hs2, csr, off[n], off[n + 1], lane, ax, ay);

    float di = dinv[n];
    float2 bb = ((const float2*)bias)[lane];
    float cx = fmaxf(fmaf(ax, di, bb.x), 0.f);   // c1[n][2*lane]   (fp32)
    float cy = fmaxf(fmaf(ay, di, bb.y), 0.f);   // c1[n][2*lane+1]

    size_t base = (size_t)n * 64;
    uint a = ((const uint*)h)[base + lane];
    uint b2 = ((const uint*)c0)[base + lane];
    int ch = lane * 2;
    float v = bflo(a) * Wout[ch]        + bfhi(a) * Wout[ch + 1] +
              bflo(b2) * Wout[128 + ch] + bfhi(b2) * Wout[128 + ch + 1] +
              cx * Wout[256 + ch]       + cy * Wout[256 + ch + 1];
#pragma unroll
    for (int o = 32; o; o >>= 1) v += __shfl_down(v, o);
    if (lane == 0) out[n] = v + bout[0];
}

// ---------------------------------------------------------------------------
extern "C" void kernel_launch(void* const* d_in, const int* in_sizes, int n_in,
                              void* d_out, int out_size, void* d_ws, size_t ws_size,
                              hipStream_t stream) {
    const float* x     = (const float*)d_in[0];
    const int*   eidx  = (const int*)d_in[1];
    const float* W_in  = (const float*)d_in[2];
    const float* b_in  = (const float*)d_in[3];
    const float* W_c0  = (const float*)d_in[4];
    const float* b_c0  = (const float*)d_in[5];
    const float* W_c1  = (const float*)d_in[6];
    const float* b_c1  = (const float*)d_in[7];
    const float* W_out = (const float*)d_in[8];
    const float* b_out = (const float*)d_in[9];
    float* out = (float*)d_out;

    const int* src = eidx;
    const int* dst = eidx + N_EDGES;

    // workspace layout (4-byte units)
    float*  ws     = (float*)d_ws;
    float*  dinv   = ws;                            // 100352
    int*    cnt    = (int*)(ws + 100352);           // 100352
    int*    off    = (int*)(ws + 200704);           // 100352 (N+1 used)
    int*    bsum   = (int*)(ws + 301056);           // 128
    int*    csr    = (int*)(ws + 301184);           // 1600000
    ushort* Wt_in  = (ushort*)(ws + 1901184);       // 32768 bf16
    ushort* Wt_c0  = (ushort*)(ws + 1917568);       // 16384 bf16
    ushort* Wt_c1  = (ushort*)(ws + 1925760);       // 16384 bf16
    ushort* h      = (ushort*)(ws + 1933952);       // 12.8M bf16
    ushort* c0     = (ushort*)(ws + 8333952);
    ushort* rank   = (ushort*)(ws + 14733952);      // 1.6M
    ushort* hs     = (ushort*)(ws + 21133952);

    // zero degree counters (graph-capture-safe async memset)
    hipMemsetAsync(cnt, 0, M_NODES * sizeof(int), stream);

    // weight prep (tiny; must precede phase1 which consumes Wt_in)
    k_prep<<<256, 256, 0, stream>>>(W_in, W_c0, W_c1, Wt_in, Wt_c0, Wt_c1);

    // phase 1: input GEMM with in-block count+rank slices
    k_phase1<<<GB, 256, 0, stream>>>(x, Wt_in, b_in, h, dst, cnt, rank);

    // scan: cnt -> off, dinv
    k_scanA<<<SCAN_NB, 256, 0, stream>>>(cnt, bsum);
    k_scanB<<<1, 128, 0, stream>>>(bsum, off);
    k_scanC<<<SCAN_NB, 256, 0, stream>>>(cnt, bsum, off, dinv);

    // phase 3: conv0 GEMM with in-block atomic-free fill slices
    k_phase3<<<GB, 256, 0, stream>>>(h, Wt_c0, dinv, hs, src, dst, off, rank, csr);

    // conv0 aggregate
    k_gather<<<(M_NODES + 3) / 4, 256, 0, stream>>>(hs, csr, off, dinv, b_c0, c0);

    // conv1 GEMM
    k_gemm<128, 1, false><<<GB, 256, 0, stream>>>(c0, Wt_c1, nullptr, dinv, hs);

    // conv1 aggregate + output head (fused)
    k_gather_out<<<(M_NODES + 3) / 4, 256, 0, stream>>>(hs, csr, off, dinv, b_c1,
                                                        h, c0, W_out, b_out, out);
}

// Round 11
// 272.103 us; speedup vs baseline: 1.1959x; 1.0405x over previous
//
#include <hip/hip_runtime.h>
#include <hip/hip_bf16.h>

#define M_NODES 100000
#define N_EDGES 1600000
#define SCAN_NB 98    // ceil(100000 / 1024)
#define GB 1563       // gemm blocks: ceil(100000/64); also edge-slice owner blocks

typedef __attribute__((ext_vector_type(8))) short short8;
typedef __attribute__((ext_vector_type(4))) float f32x4;
typedef __attribute__((ext_vector_type(2))) float f32x2;
typedef __attribute__((address_space(3))) void lds_t;
typedef const __attribute__((address_space(1))) void gld_t;

__device__ __forceinline__ ushort f2bf(float f) {
    union { float f; uint u; } x; x.f = f;
    uint r = x.u + 0x7fffu + ((x.u >> 16) & 1u);   // RNE
    return (ushort)(r >> 16);
}
__device__ __forceinline__ float bflo(uint v) {
    union { uint u; float f; } x; x.u = v << 16; return x.f;
}
__device__ __forceinline__ float bfhi(uint v) {
    union { uint u; float f; } x; x.u = v & 0xffff0000u; return x.f;
}

// ---------------------------------------------------------------------------
// weight prep (transpose + bf16), tiny standalone
// ---------------------------------------------------------------------------
__global__ void __launch_bounds__(256)
k_prep(const float* __restrict__ W_in, const float* __restrict__ W_c0,
       const float* __restrict__ W_c1, ushort* __restrict__ Wt_in,
       ushort* __restrict__ Wt_c0, ushort* __restrict__ Wt_c1) {
    const int b = blockIdx.x, t = threadIdx.x;
    if (b < 128) {
        int i = b * 256 + t;              // c = i>>8, k = i&255
        Wt_in[i] = f2bf(W_in[(size_t)(i & 255) * 128 + (i >> 8)]);
    } else if (b < 192) {
        int i = (b - 128) * 256 + t;      // c = i>>7, k = i&127
        Wt_c0[i] = f2bf(W_c0[(size_t)(i & 127) * 128 + (i >> 7)]);
    } else {
        int i = (b - 192) * 256 + t;
        Wt_c1[i] = f2bf(W_c1[(size_t)(i & 127) * 128 + (i >> 7)]);
    }
}

// ---------------------------------------------------------------------------
// 3-phase exclusive scan (off) + dinv
// ---------------------------------------------------------------------------
__global__ void __launch_bounds__(256)
k_scanA(const int* __restrict__ cnt, int* __restrict__ bsum) {
    __shared__ int sh[256];
    const int b = blockIdx.x, t = threadIdx.x;
    int base = b * 1024 + t * 4;
    int s = 0;
#pragma unroll
    for (int j = 0; j < 4; ++j) {
        int i = base + j;
        if (i < M_NODES) s += cnt[i];
    }
    sh[t] = s;
    __syncthreads();
    for (int o = 128; o; o >>= 1) {
        if (t < o) sh[t] += sh[t + o];
        __syncthreads();
    }
    if (t == 0) bsum[b] = sh[0];
}

__global__ void __launch_bounds__(128)
k_scanB(int* __restrict__ bsum, int* __restrict__ off) {
    __shared__ int sh[128];
    const int t = threadIdx.x;
    int v = (t < SCAN_NB) ? bsum[t] : 0;
    sh[t] = v;
    __syncthreads();
    for (int o = 1; o < 128; o <<= 1) {
        int u = (t >= o) ? sh[t - o] : 0;
        __syncthreads();
        sh[t] += u;
        __syncthreads();
    }
    if (t < SCAN_NB) bsum[t] = sh[t] - v;  // exclusive
    if (t == 0) off[M_NODES] = N_EDGES;
}

__global__ void __launch_bounds__(256)
k_scanC(const int* __restrict__ cnt, const int* __restrict__ bsum,
        int* __restrict__ off, float* __restrict__ dinv) {
    __shared__ int sh[256];
    const int b = blockIdx.x, t = threadIdx.x;
    int base = b * 1024 + t * 4;
    int loc[4];
    int s = 0;
#pragma unroll
    for (int j = 0; j < 4; ++j) {
        int i = base + j;
        loc[j] = (i < M_NODES) ? cnt[i] : 0;
        s += loc[j];
    }
    sh[t] = s;
    __syncthreads();
    for (int o = 1; o < 256; o <<= 1) {
        int u = (t >= o) ? sh[t - o] : 0;
        __syncthreads();
        sh[t] += u;
        __syncthreads();
    }
    int run = bsum[b] + sh[t] - s;
#pragma unroll
    for (int j = 0; j < 4; ++j) {
        int i = base + j;
        if (i < M_NODES) {
            off[i] = run;
            dinv[i] = rsqrtf((float)(loc[j] + 1));
            run += loc[j];
        }
    }
}

// ---------------------------------------------------------------------------
// MFMA GEMM body: A[M,K] @ B[K,128], Bt[128][K] bf16.
// 64x128 tile, BK=64, 4 waves (2x2): wave = 32 rows x 64 cols, 2x4 frags.
// MODE 0: out = bf16(relu(A@B + bias));  MODE 1: out = bf16((A@B)*dinv[row])
// ---------------------------------------------------------------------------
template <int K, int MODE, bool AF32>
__device__ __forceinline__ void
gemm_body(int bid, const void* __restrict__ Av, const ushort* __restrict__ Bt,
          const float* __restrict__ bias, const float* __restrict__ dinv,
          ushort* __restrict__ out) {
    __shared__ ushort As[64 * 64];    // [row][k] 8 KB
    __shared__ ushort Bs[128 * 64];   // [col][k] 16 KB
    const int t = threadIdx.x;
    const int lane = t & 63, w = t >> 6;
    const int wr = w >> 1, wc = w & 1;
    const int l15 = lane & 15, l4 = lane >> 4;
    const int row0 = bid * 64;

    f32x4 acc[2][4] = {};

    for (int k0 = 0; k0 < K; k0 += 64) {
#pragma unroll
        for (int i = 0; i < 4; ++i) {
            int idx = (i * 256 + t) * 8;          // bf16 elem index in tile
            int col = idx >> 6, kc = idx & 63;
            __builtin_amdgcn_global_load_lds(
                (gld_t*)(Bt + (size_t)col * K + k0 + kc),
                (lds_t*)(Bs + idx), 16, 0, 0);
        }
        if (AF32) {
            const float* A = (const float*)Av;
#pragma unroll
            for (int i = 0; i < 2; ++i) {
                int idx = (i * 256 + t) * 8;
                int r = idx >> 6, c = idx & 63;
                int gr = row0 + r; gr = gr < M_NODES ? gr : M_NODES - 1;
                const float4* gp = (const float4*)(A + (size_t)gr * K + k0 + c);
                float4 v0 = gp[0], v1 = gp[1];
                short8 p;
                p[0] = (short)f2bf(v0.x); p[1] = (short)f2bf(v0.y);
                p[2] = (short)f2bf(v0.z); p[3] = (short)f2bf(v0.w);
                p[4] = (short)f2bf(v1.x); p[5] = (short)f2bf(v1.y);
                p[6] = (short)f2bf(v1.z); p[7] = (short)f2bf(v1.w);
                *reinterpret_cast<short8*>(&As[idx]) = p;
            }
        } else {
            const ushort* A = (const ushort*)Av;
#pragma unroll
            for (int i = 0; i < 2; ++i) {
                int idx = (i * 256 + t) * 8;
                int r = idx >> 6, c = idx & 63;
                int gr = row0 + r; gr = gr < M_NODES ? gr : M_NODES - 1;
                __builtin_amdgcn_global_load_lds(
                    (gld_t*)(A + (size_t)gr * K + k0 + c),
                    (lds_t*)(As + idx), 16, 0, 0);
            }
        }
        __syncthreads();
#pragma unroll
        for (int kk = 0; kk < 2; ++kk) {
            short8 af[2], bw[4];
#pragma unroll
            for (int m = 0; m < 2; ++m)
                af[m] = *reinterpret_cast<const short8*>(
                    &As[(wr * 32 + m * 16 + l15) * 64 + kk * 32 + l4 * 8]);
#pragma unroll
            for (int n = 0; n < 4; ++n)
                bw[n] = *reinterpret_cast<const short8*>(
                    &Bs[(wc * 64 + n * 16 + l15) * 64 + kk * 32 + l4 * 8]);
#pragma unroll
            for (int m = 0; m < 2; ++m)
#pragma unroll
                for (int n = 0; n < 4; ++n)
                    acc[m][n] = __builtin_amdgcn_mfma_f32_16x16x32_bf16(
                        af[m], bw[n], acc[m][n], 0, 0, 0);
        }
        __syncthreads();
    }

    // epilogue: C[row][col], col = lane&15, row = (lane>>4)*4 + j
#pragma unroll
    for (int m = 0; m < 2; ++m) {
#pragma unroll
        for (int j = 0; j < 4; ++j) {
            int r = row0 + wr * 32 + m * 16 + l4 * 4 + j;
            if (r < M_NODES) {
                float sc = (MODE == 1) ? dinv[r] : 0.f;
#pragma unroll
                for (int n = 0; n < 4; ++n) {
                    int c = wc * 64 + n * 16 + l15;
                    float v = acc[m][n][j];
                    if (MODE == 0) v = fmaxf(v + bias[c], 0.f);
                    else v *= sc;
                    out[(size_t)r * 128 + c] = f2bf(v);
                }
            }
        }
    }
}

// ---------------------------------------------------------------------------
// edge-slice helpers (4 edges/thread per block slice; GB*1024 >= N_EDGES)
// ---------------------------------------------------------------------------
__device__ __forceinline__ void
count_slice(int bid, const int* __restrict__ dst, int* __restrict__ cnt,
            ushort* __restrict__ rank) {
    const int base = bid * 1024 + threadIdx.x;
    int d[4]; bool ok[4]; int r[4];
#pragma unroll
    for (int i = 0; i < 4; ++i) {
        int e = base + i * 256;
        ok[i] = e < N_EDGES;
        d[i] = ok[i] ? dst[e] : 0;
    }
#pragma unroll
    for (int i = 0; i < 4; ++i)
        if (ok[i]) r[i] = atomicAdd(&cnt[d[i]], 1);
#pragma unroll
    for (int i = 0; i < 4; ++i)
        if (ok[i]) rank[base + i * 256] = (ushort)r[i];
}

__device__ __forceinline__ void
fill_slice(int bid, const int* __restrict__ src, const int* __restrict__ dst,
           const int* __restrict__ off, const ushort* __restrict__ rank,
           int* __restrict__ csr) {
    const int base = bid * 1024 + threadIdx.x;
    int d[4], s[4]; ushort r[4]; bool ok[4]; int o[4];
#pragma unroll
    for (int i = 0; i < 4; ++i) {
        int e = base + i * 256;
        ok[i] = e < N_EDGES;
        d[i] = ok[i] ? dst[e] : 0;
        s[i] = ok[i] ? src[e] : 0;
        r[i] = ok[i] ? rank[e] : 0;
    }
#pragma unroll
    for (int i = 0; i < 4; ++i) o[i] = ok[i] ? off[d[i]] : 0;
#pragma unroll
    for (int i = 0; i < 4; ++i)
        if (ok[i]) csr[o[i] + (int)r[i]] = s[i];
}

// ---------------------------------------------------------------------------
// phase 1: input GEMM + count+rank slice, STAGGERED by block parity so one
// half's atomic burst overlaps the other half's GEMM window (atomics use the
// fabric pipe, GEMM uses MFMA/LDS - they co-schedule across waves on a CU).
// ---------------------------------------------------------------------------
__global__ void __launch_bounds__(256)
k_phase1(const float* __restrict__ x, const ushort* __restrict__ Wt_in,
         const float* __restrict__ b_in, ushort* __restrict__ h,
         const int* __restrict__ dst, int* __restrict__ cnt,
         ushort* __restrict__ rank) {
    if (blockIdx.x & 1) {
        count_slice(blockIdx.x, dst, cnt, rank);
        gemm_body<256, 0, true>(blockIdx.x, x, Wt_in, b_in, nullptr, h);
    } else {
        gemm_body<256, 0, true>(blockIdx.x, x, Wt_in, b_in, nullptr, h);
        count_slice(blockIdx.x, dst, cnt, rank);
    }
}

// ---------------------------------------------------------------------------
// phase 3: conv0 GEMM + atomic-free CSR fill slice, same stagger.
// ---------------------------------------------------------------------------
__global__ void __launch_bounds__(256)
k_phase3(const ushort* __restrict__ h, const ushort* __restrict__ Wt_c0,
         const float* __restrict__ dinv, ushort* __restrict__ hs,
         const int* __restrict__ src, const int* __restrict__ dst,
         const int* __restrict__ off, const ushort* __restrict__ rank,
         int* __restrict__ csr) {
    if (blockIdx.x & 1) {
        fill_slice(blockIdx.x, src, dst, off, rank, csr);
        gemm_body<128, 1, false>(blockIdx.x, h, Wt_c0, nullptr, dinv, hs);
    } else {
        gemm_body<128, 1, false>(blockIdx.x, h, Wt_c0, nullptr, dinv, hs);
        fill_slice(blockIdx.x, src, dst, off, rank, csr);
    }
}

template <int K, int MODE, bool AF32>
__global__ void __launch_bounds__(256)
k_gemm(const void* __restrict__ Av, const ushort* __restrict__ Bt,
       const float* __restrict__ bias, const float* __restrict__ dinv,
       ushort* __restrict__ out) {
    gemm_body<K, MODE, AF32>(blockIdx.x, Av, Bt, bias, dinv, out);
}

// ---------------------------------------------------------------------------
// neighbor accumulation core: readlane -> uniform SGPR row base (SALU addr),
// 8 loads in flight, f32x2 accumulators, static indices only.
// ---------------------------------------------------------------------------
__device__ __forceinline__ void
gather_accum(const uint* __restrict__ hs2, const int* __restrict__ csr,
             int beg, int end, int lane, float& ax, float& ay) {
    f32x2 acc[8] = {};
    for (int b = beg; b < end; b += 64) {
        int m = end - b; if (m > 64) m = 64;
        int idx = (lane < m) ? csr[b + lane] : 0;
        int i = 0;
        for (; i + 8 <= m; i += 8) {
            const uint* r0 = hs2 + ((size_t)(uint)__builtin_amdgcn_readlane(idx, i + 0) << 6);
            const uint* r1 = hs2 + ((size_t)(uint)__builtin_amdgcn_readlane(idx, i + 1) << 6);
            const uint* r2 = hs2 + ((size_t)(uint)__builtin_amdgcn_readlane(idx, i + 2) << 6);
            const uint* r3 = hs2 + ((size_t)(uint)__builtin_amdgcn_readlane(idx, i + 3) << 6);
            const uint* r4 = hs2 + ((size_t)(uint)__builtin_amdgcn_readlane(idx, i + 4) << 6);
            const uint* r5 = hs2 + ((size_t)(uint)__builtin_amdgcn_readlane(idx, i + 5) << 6);
            const uint* r6 = hs2 + ((size_t)(uint)__builtin_amdgcn_readlane(idx, i + 6) << 6);
            const uint* r7 = hs2 + ((size_t)(uint)__builtin_amdgcn_readlane(idx, i + 7) << 6);
            uint v0 = r0[lane], v1 = r1[lane], v2 = r2[lane], v3 = r3[lane];
            uint v4 = r4[lane], v5 = r5[lane], v6 = r6[lane], v7 = r7[lane];
            acc[0] += (f32x2){bflo(v0), bfhi(v0)};
            acc[1] += (f32x2){bflo(v1), bfhi(v1)};
            acc[2] += (f32x2){bflo(v2), bfhi(v2)};
            acc[3] += (f32x2){bflo(v3), bfhi(v3)};
            acc[4] += (f32x2){bflo(v4), bfhi(v4)};
            acc[5] += (f32x2){bflo(v5), bfhi(v5)};
            acc[6] += (f32x2){bflo(v6), bfhi(v6)};
            acc[7] += (f32x2){bflo(v7), bfhi(v7)};
        }
        // tail <= 7: static unroll, uniform guards, static acc indices
#pragma unroll
        for (int k = 0; k < 7; ++k) {
            if (i + k < m) {
                const uint* r = hs2 + ((size_t)(uint)__builtin_amdgcn_readlane(idx, i + k) << 6);
                uint v = r[lane];
                acc[k] += (f32x2){bflo(v), bfhi(v)};
            }
        }
    }
    f32x2 s = ((acc[0] + acc[1]) + (acc[2] + acc[3])) +
              ((acc[4] + acc[5]) + (acc[6] + acc[7]));
    ax += s.x;
    ay += s.y;
}

// ---------------------------------------------------------------------------
// gather-aggregate (bf16): one wave per node, uint (2 bf16) per lane
// ---------------------------------------------------------------------------
__global__ void __launch_bounds__(256)
k_gather(const ushort* __restrict__ hs, const int* __restrict__ csr,
         const int* __restrict__ off, const float* __restrict__ dinv,
         const float* __restrict__ bias, ushort* __restrict__ out) {
    const int wid = threadIdx.x >> 6;
    const int lane = threadIdx.x & 63;
    const int n = blockIdx.x * 4 + wid;
    if (n >= M_NODES) return;

    const uint* hs2 = (const uint*)hs;
    uint self = hs2[(size_t)n * 64 + lane];
    float ax = bflo(self), ay = bfhi(self);
    gather_accum(hs2, csr, off[n], off[n + 1], lane, ax, ay);

    float di = dinv[n];
    float2 bb = ((const float2*)bias)[lane];
    uint rx = f2bf(fmaxf(fmaf(ax, di, bb.x), 0.f));
    uint ry = f2bf(fmaxf(fmaf(ay, di, bb.y), 0.f));
    ((uint*)out)[(size_t)n * 64 + lane] = rx | (ry << 16);
}

// ---------------------------------------------------------------------------
// gather1 + output head fused: compute c1 row in regs, emit out[n] directly
// ---------------------------------------------------------------------------
__global__ void __launch_bounds__(256)
k_gather_out(const ushort* __restrict__ hs, const int* __restrict__ csr,
             const int* __restrict__ off, const float* __restrict__ dinv,
             const float* __restrict__ bias, const ushort* __restrict__ h,
             const ushort* __restrict__ c0, const float* __restrict__ Wout,
             const float* __restrict__ bout, float* __restrict__ out) {
    const int wid = threadIdx.x >> 6;
    const int lane = threadIdx.x & 63;
    const int n = blockIdx.x * 4 + wid;
    if (n >= M_NODES) return;

    const uint* hs2 = (const uint*)hs;
    uint self = hs2[(size_t)n * 64 + lane];
    float ax = bflo(self), ay = bfhi(self);
    gather_accum(hs2, csr, off[n], off[n + 1], lane, ax, ay);

    float di = dinv[n];
    float2 bb = ((const float2*)bias)[lane];
    float cx = fmaxf(fmaf(ax, di, bb.x), 0.f);   // c1[n][2*lane]   (fp32)
    float cy = fmaxf(fmaf(ay, di, bb.y), 0.f);   // c1[n][2*lane+1]

    size_t base = (size_t)n * 64;
    uint a = ((const uint*)h)[base + lane];
    uint b2 = ((const uint*)c0)[base + lane];
    int ch = lane * 2;
    float v = bflo(a) * Wout[ch]        + bfhi(a) * Wout[ch + 1] +
              bflo(b2) * Wout[128 + ch] + bfhi(b2) * Wout[128 + ch + 1] +
              cx * Wout[256 + ch]       + cy * Wout[256 + ch + 1];
#pragma unroll
    for (int o = 32; o; o >>= 1) v += __shfl_down(v, o);
    if (lane == 0) out[n] = v + bout[0];
}

// ---------------------------------------------------------------------------
extern "C" void kernel_launch(void* const* d_in, const int* in_sizes, int n_in,
                              void* d_out, int out_size, void* d_ws, size_t ws_size,
                              hipStream_t stream) {
    const float* x     = (const float*)d_in[0];
    const int*   eidx  = (const int*)d_in[1];
    const float* W_in  = (const float*)d_in[2];
    const float* b_in  = (const float*)d_in[3];
    const float* W_c0  = (const float*)d_in[4];
    const float* b_c0  = (const float*)d_in[5];
    const float* W_c1  = (const float*)d_in[6];
    const float* b_c1  = (const float*)d_in[7];
    const float* W_out = (const float*)d_in[8];
    const float* b_out = (const float*)d_in[9];
    float* out = (float*)d_out;

    const int* src = eidx;
    const int* dst = eidx + N_EDGES;

    // workspace layout (4-byte units)
    float*  ws     = (float*)d_ws;
    float*  dinv   = ws;                            // 100352
    int*    cnt    = (int*)(ws + 100352);           // 100352
    int*    off    = (int*)(ws + 200704);           // 100352 (N+1 used)
    int*    bsum   = (int*)(ws + 301056);           // 128
    int*    csr    = (int*)(ws + 301184);           // 1600000
    ushort* Wt_in  = (ushort*)(ws + 1901184);       // 32768 bf16
    ushort* Wt_c0  = (ushort*)(ws + 1917568);       // 16384 bf16
    ushort* Wt_c1  = (ushort*)(ws + 1925760);       // 16384 bf16
    ushort* h      = (ushort*)(ws + 1933952);       // 12.8M bf16
    ushort* c0     = (ushort*)(ws + 8333952);
    ushort* rank   = (ushort*)(ws + 14733952);      // 1.6M
    ushort* hs     = (ushort*)(ws + 21133952);

    // zero degree counters (graph-capture-safe async memset)
    hipMemsetAsync(cnt, 0, M_NODES * sizeof(int), stream);

    // weight prep (tiny; must precede phase1 which consumes Wt_in)
    k_prep<<<256, 256, 0, stream>>>(W_in, W_c0, W_c1, Wt_in, Wt_c0, Wt_c1);

    // phase 1: input GEMM || count+rank (block-parity staggered)
    k_phase1<<<GB, 256, 0, stream>>>(x, Wt_in, b_in, h, dst, cnt, rank);

    // scan: cnt -> off, dinv
    k_scanA<<<SCAN_NB, 256, 0, stream>>>(cnt, bsum);
    k_scanB<<<1, 128, 0, stream>>>(bsum, off);
    k_scanC<<<SCAN_NB, 256, 0, stream>>>(cnt, bsum, off, dinv);

    // phase 3: conv0 GEMM || CSR fill (block-parity staggered)
    k_phase3<<<GB, 256, 0, stream>>>(h, Wt_c0, dinv, hs, src, dst, off, rank, csr);

    // conv0 aggregate
    k_gather<<<(M_NODES + 3) / 4, 256, 0, stream>>>(hs, csr, off, dinv, b_c0, c0);

    // conv1 GEMM
    k_gemm<128, 1, false><<<GB, 256, 0, stream>>>(c0, Wt_c1, nullptr, dinv, hs);

    // conv1 aggregate + output head (fused)
    k_gather_out<<<(M_NODES + 3) / 4, 256, 0, stream>>>(hs, csr, off, dinv, b_c1,
                                                        h, c0, W_out, b_out, out);
}